// Round 3
// baseline (17965.897 us; speedup 1.0000x reference)
//
#include <hip/hip_runtime.h>
#include <hip/hip_bf16.h>
#include <math.h>

#define BB 8
#define TT 512
#define CC 512
#define HH 8
#define DH 64
#define LL 2
#define VV 512
#define NSTEPS 4
#define BT (BB*TT)
#define FF (4*CC)

// ---------------- embedding: x[bt,c] = tok[idx[bt],c] + pos[t,c] ----------------
__global__ void embed_kernel(const int* __restrict__ idx, const float* __restrict__ tok,
                             const float* __restrict__ pos, float* __restrict__ x) {
    int bt = blockIdx.x;          // 0..4095
    int t  = threadIdx.x;         // 0..255
    int token = idx[bt];
    int posrow = bt % TT;
    x[(size_t)bt*CC + t]       = tok[token*CC + t]       + pos[posrow*CC + t];
    x[(size_t)bt*CC + t + 256] = tok[token*CC + t + 256] + pos[posrow*CC + t + 256];
}

// ---------------- layernorm (one block per row, C=512, 256 threads) ----------------
__global__ void ln_kernel(const float* __restrict__ x, const float* __restrict__ g,
                          const float* __restrict__ b, float* __restrict__ out) {
    int row = blockIdx.x;
    int t = threadIdx.x;
    const float* xr = x + (size_t)row * CC;
    float v0 = xr[t], v1 = xr[t + 256];
    __shared__ float rs[256], rq[256];
    rs[t] = v0 + v1;
    rq[t] = v0 * v0 + v1 * v1;
    __syncthreads();
    for (int off = 128; off > 0; off >>= 1) {
        if (t < off) { rs[t] += rs[t + off]; rq[t] += rq[t + off]; }
        __syncthreads();
    }
    float mean = rs[0] * (1.0f / CC);
    float var  = rq[0] * (1.0f / CC) - mean * mean;
    float inv  = rsqrtf(var + 1e-5f);
    out[(size_t)row*CC + t]       = (v0 - mean) * inv * g[t]       + b[t];
    out[(size_t)row*CC + t + 256] = (v1 - mean) * inv * g[t + 256] + b[t + 256];
}

// ---------------- generic tiled GEMM: out = A[MxK] @ W[KxN] (+bias)(+residual)(GELU) ----------------
template<bool GELU>
__global__ void gemm_kernel(const float* __restrict__ A, const float* __restrict__ W,
                            const float* __restrict__ bias, const float* __restrict__ residual,
                            float* __restrict__ out, int M, int N, int K) {
    __shared__ float As[16][17];
    __shared__ float Ws[16][17];
    int tx = threadIdx.x, ty = threadIdx.y;
    int row = blockIdx.y * 16 + ty;
    int col = blockIdx.x * 16 + tx;
    float acc = 0.0f;
    for (int kt = 0; kt < K; kt += 16) {
        As[ty][tx] = A[(size_t)row * K + kt + tx];
        Ws[ty][tx] = W[(size_t)(kt + ty) * N + col];
        __syncthreads();
#pragma unroll
        for (int kk = 0; kk < 16; kk++) acc += As[ty][kk] * Ws[kk][tx];
        __syncthreads();
    }
    float val = acc;
    if (bias) val += bias[col];
    if (residual) val += residual[(size_t)row * N + col];
    if (GELU) val = 0.5f * val * (1.0f + erff(val * 0.70710678118654752f));
    out[(size_t)row * N + col] = val;
}

// ---------------- fused attention: one wave per (q-row, head, batch) ----------------
// Q,K,V: [BT, C] fp32, head h occupies cols h*64..h*64+63.  Full attention (no mask).
__global__ void attn_kernel(const float* __restrict__ Q, const float* __restrict__ K,
                            const float* __restrict__ V, float* __restrict__ Y) {
    int qi = blockIdx.x;   // 0..511
    int h  = blockIdx.y;   // 0..7
    int b  = blockIdx.z;   // 0..7
    int t  = threadIdx.x;  // 0..63
    __shared__ float qs[DH];
    __shared__ float p[TT];
    const size_t base = ((size_t)b * TT) * CC + h * DH;
    qs[t] = Q[base + (size_t)qi * CC + t];
    __syncthreads();
    const float scale = 0.125f; // 1/sqrt(64)
    float lmax = -INFINITY;
    for (int kk = t; kk < TT; kk += 64) {
        const float* krow = K + base + (size_t)kk * CC;
        float s = 0.0f;
#pragma unroll
        for (int d = 0; d < DH; d++) s += qs[d] * krow[d];
        s *= scale;
        p[kk] = s;
        lmax = fmaxf(lmax, s);
    }
#pragma unroll
    for (int off = 32; off > 0; off >>= 1) lmax = fmaxf(lmax, __shfl_xor(lmax, off));
    float lsum = 0.0f;
    for (int kk = t; kk < TT; kk += 64) {
        float e = __expf(p[kk] - lmax);
        p[kk] = e;
        lsum += e;
    }
#pragma unroll
    for (int off = 32; off > 0; off >>= 1) lsum += __shfl_xor(lsum, off);
    float inv = 1.0f / lsum;
    __syncthreads();
    // PV: thread t handles output dim d = t
    float acc = 0.0f;
    for (int kk = 0; kk < TT; kk++) acc += p[kk] * V[base + (size_t)kk * CC + t];
    Y[base + (size_t)qi * CC + t] = acc * inv;
}

extern "C" void kernel_launch(void* const* d_in, const int* in_sizes, int n_in,
                              void* d_out, int out_size, void* d_ws, size_t ws_size,
                              hipStream_t stream) {
    const int*   idx   = (const int*)d_in[0];
    const float* tok   = (const float*)d_in[1];
    const float* pos   = (const float*)d_in[2];
    const float* ln1g  = (const float*)d_in[3];
    const float* ln1b  = (const float*)d_in[4];
    const float* Wq    = (const float*)d_in[5];
    const float* bq    = (const float*)d_in[6];
    const float* Wk    = (const float*)d_in[7];
    const float* bk    = (const float*)d_in[8];
    const float* Wv    = (const float*)d_in[9];
    const float* bv    = (const float*)d_in[10];
    const float* Wp    = (const float*)d_in[11];
    const float* bp    = (const float*)d_in[12];
    const float* ln2g  = (const float*)d_in[13];
    const float* ln2b  = (const float*)d_in[14];
    const float* W1    = (const float*)d_in[15];
    const float* b1    = (const float*)d_in[16];
    const float* W2    = (const float*)d_in[17];
    const float* b2    = (const float*)d_in[18];
    const float* lnfg  = (const float*)d_in[19];
    const float* lnfb  = (const float*)d_in[20];
    const float* Whead = (const float*)d_in[21];

    // workspace layout: 6 units of BT*CC floats = 48 MB total.
    // units: u0=x, u1=xn, u2=q, u3=k, u4=v, u5=spare; hb aliases u2..u5 (MLP phase,
    // q/k/v dead by then).  No trailing-backslash comments here (line-splice trap!).
    const size_t U = (size_t)BT * CC;
    float* x  = (float*)d_ws;
    float* xn = x  + U;
    float* q  = xn + U;
    float* k  = q  + U;
    float* v  = k  + U;
    float* hb = q;   // BT*FF floats spanning u2..u5

    dim3 blk16(16, 16);
    dim3 gemm_512(VV / 16, BT / 16);     // N=512
    dim3 gemm_ff(FF / 16, BT / 16);      // N=2048

    embed_kernel<<<BT, 256, 0, stream>>>(idx, tok, pos, x);

    for (int s = 0; s < NSTEPS; s++) {
        for (int l = 0; l < LL; l++) {
            const float* wq = Wq + (size_t)l * CC * CC;
            const float* wk = Wk + (size_t)l * CC * CC;
            const float* wv = Wv + (size_t)l * CC * CC;
            const float* wp = Wp + (size_t)l * CC * CC;
            const float* w1 = W1 + (size_t)l * CC * FF;
            const float* w2 = W2 + (size_t)l * FF * CC;

            // attention
            ln_kernel<<<BT, 256, 0, stream>>>(x, ln1g + l*CC, ln1b + l*CC, xn);
            gemm_kernel<false><<<gemm_512, blk16, 0, stream>>>(xn, wq, bq + l*CC, nullptr, q, BT, CC, CC);
            gemm_kernel<false><<<gemm_512, blk16, 0, stream>>>(xn, wk, bk + l*CC, nullptr, k, BT, CC, CC);
            gemm_kernel<false><<<gemm_512, blk16, 0, stream>>>(xn, wv, bv + l*CC, nullptr, v, BT, CC, CC);
            float* y = xn; // reuse u1 (LN output already consumed by q/k/v gemms)
            attn_kernel<<<dim3(TT, HH, BB), 64, 0, stream>>>(q, k, v, y);
            gemm_kernel<false><<<gemm_512, blk16, 0, stream>>>(y, wp, bp + l*CC, x, x, BT, CC, CC);

            // MLP
            float* xn2 = xn; // reuse u1 (free after proj)
            ln_kernel<<<BT, 256, 0, stream>>>(x, ln2g + l*CC, ln2b + l*CC, xn2);
            gemm_kernel<true><<<gemm_ff, blk16, 0, stream>>>(xn2, w1, b1 + (size_t)l*FF, nullptr, hb, BT, FF, CC);
            gemm_kernel<false><<<gemm_512, blk16, 0, stream>>>(hb, w2, b2 + l*CC, x, x, BT, CC, FF);
        }
    }

    // final LN + head (output is fp32 logits [BT, V])
    float* xnf = xn;
    ln_kernel<<<BT, 256, 0, stream>>>(x, lnfg, lnfb, xnf);
    gemm_kernel<false><<<gemm_512, blk16, 0, stream>>>(xnf, Whead, nullptr, nullptr, (float*)d_out, BT, VV, CC);
}

// Round 4
// 1619.007 us; speedup vs baseline: 11.0969x; 11.0969x over previous
//
#include <hip/hip_runtime.h>
#include <hip/hip_bf16.h>
#include <math.h>

#define BB 8
#define TT 512
#define CC 512
#define HH 8
#define DH 64
#define LL 2
#define VV 512
#define NSTEPS 4
#define BT (BB*TT)
#define FF (4*CC)

typedef unsigned short u16;
typedef __bf16 bf16x8 __attribute__((ext_vector_type(8)));
typedef float f32x4 __attribute__((ext_vector_type(4)));

// fp32 -> bf16 bits, round-to-nearest-even
static __device__ __forceinline__ u16 f2bf(float f) {
    unsigned int u = __float_as_uint(f);
    unsigned int r = (u + 0x7fffu + ((u >> 16) & 1u)) >> 16;
    return (u16)r;
}

// async global->LDS, 16 bytes per lane (global_load_lds_dwordx4)
static __device__ __forceinline__ void async16(const void* g, void* l) {
    __builtin_amdgcn_global_load_lds((__attribute__((address_space(1))) void*)g,
                                     (__attribute__((address_space(3))) void*)l, 16, 0, 0);
}

// ---------------- embedding ----------------
__global__ void embed_kernel(const int* __restrict__ idx, const float* __restrict__ tok,
                             const float* __restrict__ pos, float* __restrict__ x) {
    int bt = blockIdx.x;
    int t  = threadIdx.x;
    int token = idx[bt];
    int posrow = bt % TT;
    x[(size_t)bt*CC + t]       = tok[token*CC + t]       + pos[posrow*CC + t];
    x[(size_t)bt*CC + t + 256] = tok[token*CC + t + 256] + pos[posrow*CC + t + 256];
}

// ---------------- layernorm fp32 in -> bf16 out ----------------
__global__ void ln_kernel(const float* __restrict__ x, const float* __restrict__ g,
                          const float* __restrict__ b, u16* __restrict__ out) {
    int row = blockIdx.x;
    int t = threadIdx.x;
    const float* xr = x + (size_t)row * CC;
    float v0 = xr[t], v1 = xr[t + 256];
    __shared__ float rs[256], rq[256];
    rs[t] = v0 + v1;
    rq[t] = v0 * v0 + v1 * v1;
    __syncthreads();
    for (int off = 128; off > 0; off >>= 1) {
        if (t < off) { rs[t] += rs[t + off]; rq[t] += rq[t + off]; }
        __syncthreads();
    }
    float mean = rs[0] * (1.0f / CC);
    float var  = rq[0] * (1.0f / CC) - mean * mean;
    float inv  = rsqrtf(var + 1e-5f);
    out[(size_t)row*CC + t]       = f2bf((v0 - mean) * inv * g[t]       + b[t]);
    out[(size_t)row*CC + t + 256] = f2bf((v1 - mean) * inv * g[t + 256] + b[t + 256]);
}

// ---------------- cast+transpose: src fp32 [K][N] -> dst bf16 [N][K] ----------------
__global__ void cast_transpose_kernel(const float* __restrict__ src, u16* __restrict__ dst,
                                      int K, int N) {
    __shared__ float tile[64][65];
    int j0 = blockIdx.x * 64;   // N offset
    int i0 = blockIdx.y * 64;   // K offset
    int t = threadIdx.x;
    int r = t >> 2;             // 0..63
    int cg = (t & 3) * 16;
#pragma unroll
    for (int i = 0; i < 16; i++)
        tile[r][cg + i] = src[(size_t)(i0 + r) * N + j0 + cg + i];
    __syncthreads();
#pragma unroll
    for (int i = 0; i < 16; i++)
        dst[(size_t)(j0 + r) * K + i0 + cg + i] = f2bf(tile[cg + i][r]);
}

// ---------------- MFMA GEMM: out = A[M,K](bf16) @ Bt[N,K]^T (+epilogue) ----------------
// EPI 0: QKV fused  (bias=bq, biask=bk, biasv=bv; outq=q, outk=k, outvt=vt[B][H][DH][T])
// EPI 1: bias + residual accumulate into fp32 outf (proj, fc2)
// EPI 2: bias + exact GELU -> bf16 outq (fc1)
// EPI 3: plain fp32 out (head)
template<int EPI>
__global__ __launch_bounds__(256)
void gemm_bt_kernel(const u16* __restrict__ A, const u16* __restrict__ Bt,
                    int N, int K,
                    const float* __restrict__ bias, const float* __restrict__ biask,
                    const float* __restrict__ biasv,
                    float* outf, u16* outq, u16* outk, u16* outvt) {
    __shared__ u16 lds_a[128][32];
    __shared__ u16 lds_b[128][32];
    int tid = threadIdx.x;
    int wid = tid >> 6, lane = tid & 63;
    int quad = lane >> 4, l15 = lane & 15;
    int wm = (wid & 1) * 64, wn = (wid >> 1) * 64;
    int bm = blockIdx.y, bn = blockIdx.x;
    const int r = tid >> 2;          // 0..63
    const int c8 = (tid & 3) * 8;    // col element offset
    f32x4 zero = {0.f, 0.f, 0.f, 0.f};
    f32x4 acc[4][4];
#pragma unroll
    for (int mi = 0; mi < 4; mi++)
#pragma unroll
        for (int ni = 0; ni < 4; ni++) acc[mi][ni] = zero;

    const size_t a0 = (size_t)bm * 128, b0 = (size_t)bn * 128;
    for (int kt = 0; kt < K; kt += 32) {
        async16(&A[(a0 + r) * K + kt + c8],        &lds_a[r][c8]);
        async16(&A[(a0 + 64 + r) * K + kt + c8],   &lds_a[64 + r][c8]);
        async16(&Bt[(b0 + r) * K + kt + c8],       &lds_b[r][c8]);
        async16(&Bt[(b0 + 64 + r) * K + kt + c8],  &lds_b[64 + r][c8]);
        __syncthreads();
        bf16x8 af[4], bfr[4];
#pragma unroll
        for (int mi = 0; mi < 4; mi++) af[mi]  = *(const bf16x8*)&lds_a[wm + mi*16 + l15][quad*8];
#pragma unroll
        for (int ni = 0; ni < 4; ni++) bfr[ni] = *(const bf16x8*)&lds_b[wn + ni*16 + l15][quad*8];
#pragma unroll
        for (int mi = 0; mi < 4; mi++)
#pragma unroll
            for (int ni = 0; ni < 4; ni++)
                acc[mi][ni] = __builtin_amdgcn_mfma_f32_16x16x32_bf16(af[mi], bfr[ni], acc[mi][ni], 0, 0, 0);
        __syncthreads();
    }

#pragma unroll
    for (int mi = 0; mi < 4; mi++)
#pragma unroll
        for (int ni = 0; ni < 4; ni++)
#pragma unroll
            for (int i = 0; i < 4; i++) {
                int row = bm*128 + wm + mi*16 + quad*4 + i;
                int col = bn*128 + wn + ni*16 + l15;
                float v = acc[mi][ni][i];
                if (EPI == 0) {
                    int region = col >> 9, cl = col & 511;
                    if (region == 0) {
                        v += bias[cl];
                        outq[(size_t)row*512 + cl] = f2bf(v);
                    } else if (region == 1) {
                        v += biask[cl];
                        outk[(size_t)row*512 + cl] = f2bf(v);
                    } else {
                        v += biasv[cl];
                        int bb = row >> 9, tpos = row & 511, hh = cl >> 6, dh = cl & 63;
                        outvt[(((size_t)(bb*8 + hh)*64 + dh) << 9) + tpos] = f2bf(v);
                    }
                } else if (EPI == 1) {
                    size_t idx2 = (size_t)row * N + col;
                    v += bias[col] + outf[idx2];
                    outf[idx2] = v;
                } else if (EPI == 2) {
                    v += bias[col];
                    v = 0.5f * v * (1.0f + erff(v * 0.70710678118654752f));
                    outq[(size_t)row * N + col] = f2bf(v);
                } else {
                    outf[(size_t)row * N + col] = v;
                }
            }
}

// ---------------- fused MFMA flash attention ----------------
// q,k: bf16 [BT][C] (head slice cols h*64..); vt: bf16 [B][H][DH][T]; y: bf16 [BT][C]
// grid (T/128, H, B), block 256 (4 waves); wave w handles q-rows w*32..w*32+31 of the tile.
__global__ __launch_bounds__(256)
void attn_mfma_kernel(const u16* __restrict__ q, const u16* __restrict__ k,
                      const u16* __restrict__ vt, u16* __restrict__ y) {
    __shared__ u16 lq[128][64];   // 16 KB
    __shared__ u16 lk[64][64];    // 8 KB
    __shared__ u16 lv[64][64];    // 8 KB  (V^T tile: [dh][key])
    __shared__ u16 lp[4][32][64]; // 16 KB (per-wave P round-trip)
    int qt = blockIdx.x, h = blockIdx.y, b = blockIdx.z;
    int tid = threadIdx.x;
    int wid = tid >> 6, lane = tid & 63;
    int quad = lane >> 4, l15 = lane & 15;
    const int sr = tid >> 3;        // 0..31 staging row within call
    const int sc = (tid & 7) * 8;   // staging col element offset

    // stage Q tile (128 rows x 64 bf16)
#pragma unroll
    for (int call = 0; call < 4; call++)
        async16(&q[(size_t)(b*TT + qt*128 + call*32 + sr)*CC + h*DH + sc], &lq[call*32 + sr][sc]);

    f32x4 zero = {0.f, 0.f, 0.f, 0.f};
    f32x4 acc_o[2][4];
    float m_st[2][4], l_st[2][4];
#pragma unroll
    for (int mi = 0; mi < 2; mi++)
#pragma unroll
        for (int i = 0; i < 4; i++) { m_st[mi][i] = -INFINITY; l_st[mi][i] = 0.f; }
#pragma unroll
    for (int mi = 0; mi < 2; mi++)
#pragma unroll
        for (int ni = 0; ni < 4; ni++) acc_o[mi][ni] = zero;

    const float SCALE = 0.125f;
    for (int kt = 0; kt < TT/64; kt++) {
        // stage K tile [64 keys][64 dh] and V^T tile [64 dh][64 keys]
#pragma unroll
        for (int call = 0; call < 2; call++) {
            async16(&k[(size_t)(b*TT + kt*64 + call*32 + sr)*CC + h*DH + sc], &lk[call*32 + sr][sc]);
            async16(&vt[((size_t)((b*HH + h)*DH + call*32 + sr))*TT + kt*64 + sc], &lv[call*32 + sr][sc]);
        }
        __syncthreads();

        // S = Q K^T  (wave: 32 q x 64 keys = 2x4 tiles, K-dim = DH = 64 = 2 steps)
        f32x4 s[2][4];
#pragma unroll
        for (int mi = 0; mi < 2; mi++)
#pragma unroll
            for (int ni = 0; ni < 4; ni++) s[mi][ni] = zero;
#pragma unroll
        for (int ks = 0; ks < 2; ks++) {
            bf16x8 af[2], bfr[4];
#pragma unroll
            for (int mi = 0; mi < 2; mi++) af[mi]  = *(const bf16x8*)&lq[wid*32 + mi*16 + l15][ks*32 + quad*8];
#pragma unroll
            for (int ni = 0; ni < 4; ni++) bfr[ni] = *(const bf16x8*)&lk[ni*16 + l15][ks*32 + quad*8];
#pragma unroll
            for (int mi = 0; mi < 2; mi++)
#pragma unroll
                for (int ni = 0; ni < 4; ni++)
                    s[mi][ni] = __builtin_amdgcn_mfma_f32_16x16x32_bf16(af[mi], bfr[ni], s[mi][ni], 0, 0, 0);
        }

        // online softmax update (per lane: rows quad*4+reg of each 16-row tile)
#pragma unroll
        for (int mi = 0; mi < 2; mi++)
#pragma unroll
            for (int i = 0; i < 4; i++) {
                float mx = -INFINITY;
#pragma unroll
                for (int ni = 0; ni < 4; ni++) {
                    s[mi][ni][i] *= SCALE;
                    mx = fmaxf(mx, s[mi][ni][i]);
                }
#pragma unroll
                for (int off = 1; off < 16; off <<= 1) mx = fmaxf(mx, __shfl_xor(mx, off));
                float mn = fmaxf(m_st[mi][i], mx);
                float al = __expf(m_st[mi][i] - mn);
                float rs = 0.f;
#pragma unroll
                for (int ni = 0; ni < 4; ni++) {
                    float p = __expf(s[mi][ni][i] - mn);
                    s[mi][ni][i] = p;
                    rs += p;
                }
#pragma unroll
                for (int off = 1; off < 16; off <<= 1) rs += __shfl_xor(rs, off);
                l_st[mi][i] = l_st[mi][i] * al + rs;
                m_st[mi][i] = mn;
#pragma unroll
                for (int ni = 0; ni < 4; ni++) acc_o[mi][ni][i] *= al;
            }

        // P -> LDS (C-layout -> A-operand layout round trip), per-wave region, no barrier
#pragma unroll
        for (int mi = 0; mi < 2; mi++)
#pragma unroll
            for (int ni = 0; ni < 4; ni++)
#pragma unroll
                for (int i = 0; i < 4; i++)
                    lp[wid][mi*16 + quad*4 + i][ni*16 + l15] = f2bf(s[mi][ni][i]);

        // O += P V  (K-dim = 64 keys = 2 steps; B = V^T rows = dh)
#pragma unroll
        for (int ks = 0; ks < 2; ks++) {
            bf16x8 pa[2], vb[4];
#pragma unroll
            for (int mi = 0; mi < 2; mi++) pa[mi] = *(const bf16x8*)&lp[wid][mi*16 + l15][ks*32 + quad*8];
#pragma unroll
            for (int ni = 0; ni < 4; ni++) vb[ni] = *(const bf16x8*)&lv[ni*16 + l15][ks*32 + quad*8];
#pragma unroll
            for (int mi = 0; mi < 2; mi++)
#pragma unroll
                for (int ni = 0; ni < 4; ni++)
                    acc_o[mi][ni] = __builtin_amdgcn_mfma_f32_16x16x32_bf16(pa[mi], vb[ni], acc_o[mi][ni], 0, 0, 0);
        }
        __syncthreads();
    }

    // normalize + write y (bf16)
#pragma unroll
    for (int mi = 0; mi < 2; mi++)
#pragma unroll
        for (int i = 0; i < 4; i++) {
            float inv = 1.0f / l_st[mi][i];
#pragma unroll
            for (int ni = 0; ni < 4; ni++) {
                int qrow = qt*128 + wid*32 + mi*16 + quad*4 + i;
                int col  = h*DH + ni*16 + l15;
                y[(size_t)(b*TT + qrow)*CC + col] = f2bf(acc_o[mi][ni][i] * inv);
            }
        }
}

extern "C" void kernel_launch(void* const* d_in, const int* in_sizes, int n_in,
                              void* d_out, int out_size, void* d_ws, size_t ws_size,
                              hipStream_t stream) {
    const int*   idx   = (const int*)d_in[0];
    const float* tok   = (const float*)d_in[1];
    const float* pos   = (const float*)d_in[2];
    const float* ln1g  = (const float*)d_in[3];
    const float* ln1b  = (const float*)d_in[4];
    const float* Wq    = (const float*)d_in[5];
    const float* bq    = (const float*)d_in[6];
    const float* Wk    = (const float*)d_in[7];
    const float* bk    = (const float*)d_in[8];
    const float* Wv    = (const float*)d_in[9];
    const float* bv    = (const float*)d_in[10];
    const float* Wp    = (const float*)d_in[11];
    const float* bp    = (const float*)d_in[12];
    const float* ln2g  = (const float*)d_in[13];
    const float* ln2b  = (const float*)d_in[14];
    const float* W1    = (const float*)d_in[15];
    const float* b1    = (const float*)d_in[16];
    const float* W2    = (const float*)d_in[17];
    const float* b2    = (const float*)d_in[18];
    const float* lnfg  = (const float*)d_in[19];
    const float* lnfb  = (const float*)d_in[20];
    const float* Whead = (const float*)d_in[21];

    // ---- workspace layout (42.5 MB) ----
    float* x  = (float*)d_ws;                       // BT*CC fp32 (8 MB)
    u16* xn   = (u16*)(x + (size_t)BT*CC);          // BT*CC bf16 (4 MB): LN out / attn y
    u16* R    = xn + (size_t)BT*CC;                 // 16 MB region
    u16* qb   = R;                                  // BT*CC
    u16* kb   = R + (size_t)BT*CC;                  // BT*CC
    u16* vtb  = R + (size_t)2*BT*CC;                // B*H*DH*T
    u16* hb   = R;                                  // BT*FF (spans whole region; q/k/vt dead)
    u16* w_qkvt = R + (size_t)4*BT*CC;              // 2 x [1536][512]
    u16* w_pt   = w_qkvt + (size_t)2*3*CC*CC;       // 2 x [512][512]
    u16* w_1t   = w_pt   + (size_t)2*CC*CC;         // 2 x [2048][512]
    u16* w_2t   = w_1t   + (size_t)2*CC*FF;         // 2 x [512][2048]
    u16* w_ht   = w_2t   + (size_t)2*FF*CC;         // [512][512]

    // ---- weight cast+transpose (once per call) ----
    for (int l = 0; l < LL; l++) {
        const size_t wcc = (size_t)CC*CC, wcf = (size_t)CC*FF;
        cast_transpose_kernel<<<dim3(CC/64, CC/64), 256, 0, stream>>>(Wq + l*wcc, w_qkvt + l*3*wcc,           CC, CC);
        cast_transpose_kernel<<<dim3(CC/64, CC/64), 256, 0, stream>>>(Wk + l*wcc, w_qkvt + l*3*wcc + wcc,     CC, CC);
        cast_transpose_kernel<<<dim3(CC/64, CC/64), 256, 0, stream>>>(Wv + l*wcc, w_qkvt + l*3*wcc + 2*wcc,   CC, CC);
        cast_transpose_kernel<<<dim3(CC/64, CC/64), 256, 0, stream>>>(Wp + l*wcc, w_pt + l*wcc,               CC, CC);
        cast_transpose_kernel<<<dim3(FF/64, CC/64), 256, 0, stream>>>(W1 + l*wcf, w_1t + l*wcf,               CC, FF);
        cast_transpose_kernel<<<dim3(CC/64, FF/64), 256, 0, stream>>>(W2 + l*wcf, w_2t + l*wcf,               FF, CC);
    }
    cast_transpose_kernel<<<dim3(CC/64, CC/64), 256, 0, stream>>>(Whead, w_ht, CC, CC);

    embed_kernel<<<BT, 256, 0, stream>>>(idx, tok, pos, x);

    for (int s = 0; s < NSTEPS; s++) {
        for (int l = 0; l < LL; l++) {
            // attention
            ln_kernel<<<BT, 256, 0, stream>>>(x, ln1g + l*CC, ln1b + l*CC, xn);
            gemm_bt_kernel<0><<<dim3(12, BT/128), 256, 0, stream>>>(
                xn, w_qkvt + (size_t)l*3*CC*CC, 3*CC, CC,
                bq + l*CC, bk + l*CC, bv + l*CC, nullptr, qb, kb, vtb);
            attn_mfma_kernel<<<dim3(TT/128, HH, BB), 256, 0, stream>>>(qb, kb, vtb, xn);
            gemm_bt_kernel<1><<<dim3(4, BT/128), 256, 0, stream>>>(
                xn, w_pt + (size_t)l*CC*CC, CC, CC,
                bp + l*CC, nullptr, nullptr, x, nullptr, nullptr, nullptr);
            // MLP
            ln_kernel<<<BT, 256, 0, stream>>>(x, ln2g + l*CC, ln2b + l*CC, xn);
            gemm_bt_kernel<2><<<dim3(16, BT/128), 256, 0, stream>>>(
                xn, w_1t + (size_t)l*CC*FF, FF, CC,
                b1 + (size_t)l*FF, nullptr, nullptr, nullptr, hb, nullptr, nullptr);
            gemm_bt_kernel<1><<<dim3(4, BT/128), 256, 0, stream>>>(
                hb, w_2t + (size_t)l*FF*CC, CC, FF,
                b2 + l*CC, nullptr, nullptr, x, nullptr, nullptr, nullptr);
        }
    }

    // final LN + head (fp32 logits)
    ln_kernel<<<BT, 256, 0, stream>>>(x, lnfg, lnfb, xn);
    gemm_bt_kernel<3><<<dim3(4, BT/128), 256, 0, stream>>>(
        xn, w_ht, VV, CC, nullptr, nullptr, nullptr, (float*)d_out, nullptr, nullptr, nullptr);
}

// Round 5
// 1165.336 us; speedup vs baseline: 15.4169x; 1.3893x over previous
//
#include <hip/hip_runtime.h>
#include <hip/hip_bf16.h>
#include <math.h>

#define BB 8
#define TT 512
#define CC 512
#define HH 8
#define DH 64
#define LL 2
#define VV 512
#define NSTEPS 4
#define BT (BB*TT)
#define FF (4*CC)

typedef unsigned short u16;
typedef __bf16 bf16x8 __attribute__((ext_vector_type(8)));
typedef float f32x4 __attribute__((ext_vector_type(4)));

// fp32 -> bf16 bits, round-to-nearest-even
static __device__ __forceinline__ u16 f2bf(float f) {
    unsigned int u = __float_as_uint(f);
    unsigned int r = (u + 0x7fffu + ((u >> 16) & 1u)) >> 16;
    return (u16)r;
}

// async global->LDS, 16 bytes per lane (global_load_lds_dwordx4)
static __device__ __forceinline__ void async16(const void* g, void* l) {
    __builtin_amdgcn_global_load_lds((__attribute__((address_space(1))) void*)g,
                                     (__attribute__((address_space(3))) void*)l, 16, 0, 0);
}

// ---------------- embedding ----------------
__global__ void embed_kernel(const int* __restrict__ idx, const float* __restrict__ tok,
                             const float* __restrict__ pos, float* __restrict__ x) {
    int bt = blockIdx.x;
    int t  = threadIdx.x;
    int token = idx[bt];
    int posrow = bt % TT;
    x[(size_t)bt*CC + t]       = tok[token*CC + t]       + pos[posrow*CC + t];
    x[(size_t)bt*CC + t + 256] = tok[token*CC + t + 256] + pos[posrow*CC + t + 256];
}

// ---------------- layernorm fp32 in -> bf16 out ----------------
__global__ void ln_kernel(const float* __restrict__ x, const float* __restrict__ g,
                          const float* __restrict__ b, u16* __restrict__ out) {
    int row = blockIdx.x;
    int t = threadIdx.x;
    const float* xr = x + (size_t)row * CC;
    float v0 = xr[t], v1 = xr[t + 256];
    __shared__ float rs[256], rq[256];
    rs[t] = v0 + v1;
    rq[t] = v0 * v0 + v1 * v1;
    __syncthreads();
    for (int off = 128; off > 0; off >>= 1) {
        if (t < off) { rs[t] += rs[t + off]; rq[t] += rq[t + off]; }
        __syncthreads();
    }
    float mean = rs[0] * (1.0f / CC);
    float var  = rq[0] * (1.0f / CC) - mean * mean;
    float inv  = rsqrtf(var + 1e-5f);
    out[(size_t)row*CC + t]       = f2bf((v0 - mean) * inv * g[t]       + b[t]);
    out[(size_t)row*CC + t + 256] = f2bf((v1 - mean) * inv * g[t + 256] + b[t + 256]);
}

// ---------------- cast+transpose: src fp32 [K][N] -> dst bf16 [N][K] ----------------
__global__ void cast_transpose_kernel(const float* __restrict__ src, u16* __restrict__ dst,
                                      int K, int N) {
    __shared__ float tile[64][65];
    int j0 = blockIdx.x * 64;   // N offset
    int i0 = blockIdx.y * 64;   // K offset
    int t = threadIdx.x;
    int r = t >> 2;             // 0..63
    int cg = (t & 3) * 16;
#pragma unroll
    for (int i = 0; i < 16; i++)
        tile[r][cg + i] = src[(size_t)(i0 + r) * N + j0 + cg + i];
    __syncthreads();
#pragma unroll
    for (int i = 0; i < 16; i++)
        dst[(size_t)(j0 + r) * K + i0 + cg + i] = f2bf(tile[cg + i][r]);
}

// ---------------- MFMA GEMM: out = A[M,K](bf16) @ Bt[N,K]^T (+epilogue) ----------------
// Tiles: BM x BN, 4 waves in 2x2, per-wave (BM/2)x(BN/2) of 16x16x32 MFMAs.
// 1-D grid with XCD swizzle: lin&7 selects bm residue so all bn-blocks of a bm
// run on the same XCD (A-tile L2 reuse; per-XCD L2 holds all of B).
// EPI 0: QKV fused  (bias=bq, biask=bk, biasv=bv; outq=q, outk=k, outvt=vt[B][H][DH][T])
// EPI 1: bias + residual accumulate into fp32 outf (proj, fc2)
// EPI 2: bias + exact GELU -> bf16 outq (fc1)
// EPI 3: plain fp32 out (head)
template<int BM, int BN, int EPI>
__global__ __launch_bounds__(256)
void gemm_bt_kernel(const u16* __restrict__ A, const u16* __restrict__ Bt,
                    int N, int K,
                    const float* __restrict__ bias, const float* __restrict__ biask,
                    const float* __restrict__ biasv,
                    float* outf, u16* outq, u16* outk, u16* outvt) {
    constexpr int WM = BM / 2, WN = BN / 2;
    constexpr int TM = WM / 16, TN = WN / 16;
    __shared__ u16 lds_a[BM][32];
    __shared__ u16 lds_b[BN][32];
    int tid = threadIdx.x;
    int wid = tid >> 6, lane = tid & 63;
    int quad = lane >> 4, l15 = lane & 15;
    int wm = (wid & 1) * WM, wn = (wid >> 1) * WN;

    // XCD swizzle decode
    int NBN = N / BN;
    int lin = blockIdx.x;
    int x8 = lin & 7, slot = lin >> 3;
    int bn = slot % NBN;
    int bm = (slot / NBN) * 8 + x8;

    const int r = tid >> 2;          // 0..63
    const int c8 = (tid & 3) * 8;    // col element offset
    f32x4 zero = {0.f, 0.f, 0.f, 0.f};
    f32x4 acc[TM][TN];
#pragma unroll
    for (int mi = 0; mi < TM; mi++)
#pragma unroll
        for (int ni = 0; ni < TN; ni++) acc[mi][ni] = zero;

    const size_t a0 = (size_t)bm * BM, b0 = (size_t)bn * BN;
    for (int kt = 0; kt < K; kt += 32) {
#pragma unroll
        for (int i = 0; i < BM/64; i++)
            async16(&A[(a0 + i*64 + r) * K + kt + c8], &lds_a[i*64 + r][c8]);
#pragma unroll
        for (int i = 0; i < BN/64; i++)
            async16(&Bt[(b0 + i*64 + r) * K + kt + c8], &lds_b[i*64 + r][c8]);
        __syncthreads();
        bf16x8 af[TM], bfr[TN];
#pragma unroll
        for (int mi = 0; mi < TM; mi++) af[mi]  = *(const bf16x8*)&lds_a[wm + mi*16 + l15][quad*8];
#pragma unroll
        for (int ni = 0; ni < TN; ni++) bfr[ni] = *(const bf16x8*)&lds_b[wn + ni*16 + l15][quad*8];
#pragma unroll
        for (int mi = 0; mi < TM; mi++)
#pragma unroll
            for (int ni = 0; ni < TN; ni++)
                acc[mi][ni] = __builtin_amdgcn_mfma_f32_16x16x32_bf16(af[mi], bfr[ni], acc[mi][ni], 0, 0, 0);
        __syncthreads();
    }

#pragma unroll
    for (int mi = 0; mi < TM; mi++)
#pragma unroll
        for (int ni = 0; ni < TN; ni++)
#pragma unroll
            for (int i = 0; i < 4; i++) {
                int row = bm*BM + wm + mi*16 + quad*4 + i;
                int col = bn*BN + wn + ni*16 + l15;
                float v = acc[mi][ni][i];
                if (EPI == 0) {
                    int region = col >> 9, cl = col & 511;
                    if (region == 0) {
                        v += bias[cl];
                        outq[(size_t)row*512 + cl] = f2bf(v);
                    } else if (region == 1) {
                        v += biask[cl];
                        outk[(size_t)row*512 + cl] = f2bf(v);
                    } else {
                        v += biasv[cl];
                        int bb = row >> 9, tpos = row & 511, hh = cl >> 6, dh = cl & 63;
                        outvt[(((size_t)(bb*8 + hh)*64 + dh) << 9) + tpos] = f2bf(v);
                    }
                } else if (EPI == 1) {
                    size_t idx2 = (size_t)row * N + col;
                    v += bias[col] + outf[idx2];
                    outf[idx2] = v;
                } else if (EPI == 2) {
                    v += bias[col];
                    v = 0.5f * v * (1.0f + erff(v * 0.70710678118654752f));
                    outq[(size_t)row * N + col] = f2bf(v);
                } else {
                    outf[(size_t)row * N + col] = v;
                }
            }
}

// ---------------- fused MFMA flash attention ----------------
// q,k: bf16 [BT][C] (head slice cols h*64..); vt: bf16 [B][H][DH][T]; y: bf16 [BT][C]
// grid (T/128, H, B), block 256 (4 waves); wave w handles q-rows w*32..w*32+31 of the tile.
__global__ __launch_bounds__(256)
void attn_mfma_kernel(const u16* __restrict__ q, const u16* __restrict__ k,
                      const u16* __restrict__ vt, u16* __restrict__ y) {
    __shared__ u16 lq[128][64];   // 16 KB
    __shared__ u16 lk[64][64];    // 8 KB
    __shared__ u16 lv[64][64];    // 8 KB  (V^T tile: [dh][key])
    __shared__ u16 lp[4][32][64]; // 16 KB (per-wave P round-trip)
    int qt = blockIdx.x, h = blockIdx.y, b = blockIdx.z;
    int tid = threadIdx.x;
    int wid = tid >> 6, lane = tid & 63;
    int quad = lane >> 4, l15 = lane & 15;
    const int sr = tid >> 3;        // 0..31 staging row within call
    const int sc = (tid & 7) * 8;   // staging col element offset

#pragma unroll
    for (int call = 0; call < 4; call++)
        async16(&q[(size_t)(b*TT + qt*128 + call*32 + sr)*CC + h*DH + sc], &lq[call*32 + sr][sc]);

    f32x4 zero = {0.f, 0.f, 0.f, 0.f};
    f32x4 acc_o[2][4];
    float m_st[2][4], l_st[2][4];
#pragma unroll
    for (int mi = 0; mi < 2; mi++)
#pragma unroll
        for (int i = 0; i < 4; i++) { m_st[mi][i] = -INFINITY; l_st[mi][i] = 0.f; }
#pragma unroll
    for (int mi = 0; mi < 2; mi++)
#pragma unroll
        for (int ni = 0; ni < 4; ni++) acc_o[mi][ni] = zero;

    const float SCALE = 0.125f;
    for (int kt = 0; kt < TT/64; kt++) {
#pragma unroll
        for (int call = 0; call < 2; call++) {
            async16(&k[(size_t)(b*TT + kt*64 + call*32 + sr)*CC + h*DH + sc], &lk[call*32 + sr][sc]);
            async16(&vt[((size_t)((b*HH + h)*DH + call*32 + sr))*TT + kt*64 + sc], &lv[call*32 + sr][sc]);
        }
        __syncthreads();

        // S = Q K^T
        f32x4 s[2][4];
#pragma unroll
        for (int mi = 0; mi < 2; mi++)
#pragma unroll
            for (int ni = 0; ni < 4; ni++) s[mi][ni] = zero;
#pragma unroll
        for (int ks = 0; ks < 2; ks++) {
            bf16x8 af[2], bfr[4];
#pragma unroll
            for (int mi = 0; mi < 2; mi++) af[mi]  = *(const bf16x8*)&lq[wid*32 + mi*16 + l15][ks*32 + quad*8];
#pragma unroll
            for (int ni = 0; ni < 4; ni++) bfr[ni] = *(const bf16x8*)&lk[ni*16 + l15][ks*32 + quad*8];
#pragma unroll
            for (int mi = 0; mi < 2; mi++)
#pragma unroll
                for (int ni = 0; ni < 4; ni++)
                    s[mi][ni] = __builtin_amdgcn_mfma_f32_16x16x32_bf16(af[mi], bfr[ni], s[mi][ni], 0, 0, 0);
        }

        // online softmax update
#pragma unroll
        for (int mi = 0; mi < 2; mi++)
#pragma unroll
            for (int i = 0; i < 4; i++) {
                float mx = -INFINITY;
#pragma unroll
                for (int ni = 0; ni < 4; ni++) {
                    s[mi][ni][i] *= SCALE;
                    mx = fmaxf(mx, s[mi][ni][i]);
                }
#pragma unroll
                for (int off = 1; off < 16; off <<= 1) mx = fmaxf(mx, __shfl_xor(mx, off));
                float mn = fmaxf(m_st[mi][i], mx);
                float al = __expf(m_st[mi][i] - mn);
                float rs = 0.f;
#pragma unroll
                for (int ni = 0; ni < 4; ni++) {
                    float p = __expf(s[mi][ni][i] - mn);
                    s[mi][ni][i] = p;
                    rs += p;
                }
#pragma unroll
                for (int off = 1; off < 16; off <<= 1) rs += __shfl_xor(rs, off);
                l_st[mi][i] = l_st[mi][i] * al + rs;
                m_st[mi][i] = mn;
#pragma unroll
                for (int ni = 0; ni < 4; ni++) acc_o[mi][ni][i] *= al;
            }

        // P -> LDS (C-layout -> A-operand layout), per-wave region
#pragma unroll
        for (int mi = 0; mi < 2; mi++)
#pragma unroll
            for (int ni = 0; ni < 4; ni++)
#pragma unroll
                for (int i = 0; i < 4; i++)
                    lp[wid][mi*16 + quad*4 + i][ni*16 + l15] = f2bf(s[mi][ni][i]);

        // O += P V
#pragma unroll
        for (int ks = 0; ks < 2; ks++) {
            bf16x8 pa[2], vb[4];
#pragma unroll
            for (int mi = 0; mi < 2; mi++) pa[mi] = *(const bf16x8*)&lp[wid][mi*16 + l15][ks*32 + quad*8];
#pragma unroll
            for (int ni = 0; ni < 4; ni++) vb[ni] = *(const bf16x8*)&lv[ni*16 + l15][ks*32 + quad*8];
#pragma unroll
            for (int mi = 0; mi < 2; mi++)
#pragma unroll
                for (int ni = 0; ni < 4; ni++)
                    acc_o[mi][ni] = __builtin_amdgcn_mfma_f32_16x16x32_bf16(pa[mi], vb[ni], acc_o[mi][ni], 0, 0, 0);
        }
        __syncthreads();
    }

#pragma unroll
    for (int mi = 0; mi < 2; mi++)
#pragma unroll
        for (int i = 0; i < 4; i++) {
            float inv = 1.0f / l_st[mi][i];
#pragma unroll
            for (int ni = 0; ni < 4; ni++) {
                int qrow = qt*128 + wid*32 + mi*16 + quad*4 + i;
                int col  = h*DH + ni*16 + l15;
                y[(size_t)(b*TT + qrow)*CC + col] = f2bf(acc_o[mi][ni][i] * inv);
            }
        }
}

extern "C" void kernel_launch(void* const* d_in, const int* in_sizes, int n_in,
                              void* d_out, int out_size, void* d_ws, size_t ws_size,
                              hipStream_t stream) {
    const int*   idx   = (const int*)d_in[0];
    const float* tok   = (const float*)d_in[1];
    const float* pos   = (const float*)d_in[2];
    const float* ln1g  = (const float*)d_in[3];
    const float* ln1b  = (const float*)d_in[4];
    const float* Wq    = (const float*)d_in[5];
    const float* bq    = (const float*)d_in[6];
    const float* Wk    = (const float*)d_in[7];
    const float* bk    = (const float*)d_in[8];
    const float* Wv    = (const float*)d_in[9];
    const float* bv    = (const float*)d_in[10];
    const float* Wp    = (const float*)d_in[11];
    const float* bp    = (const float*)d_in[12];
    const float* ln2g  = (const float*)d_in[13];
    const float* ln2b  = (const float*)d_in[14];
    const float* W1    = (const float*)d_in[15];
    const float* b1    = (const float*)d_in[16];
    const float* W2    = (const float*)d_in[17];
    const float* b2    = (const float*)d_in[18];
    const float* lnfg  = (const float*)d_in[19];
    const float* lnfb  = (const float*)d_in[20];
    const float* Whead = (const float*)d_in[21];

    // ---- workspace layout (~40.5 MB) ----
    float* x  = (float*)d_ws;                       // BT*CC fp32 (8 MB)
    u16* xn   = (u16*)(x + (size_t)BT*CC);          // BT*CC bf16 (4 MB)
    u16* R    = xn + (size_t)BT*CC;                 // 16 MB region
    u16* qb   = R;
    u16* kb   = R + (size_t)BT*CC;
    u16* vtb  = R + (size_t)2*BT*CC;
    u16* hb   = R;                                  // BT*FF spans region (q/k/vt dead in MLP)
    u16* w_qkvt = R + (size_t)4*BT*CC;
    u16* w_pt   = w_qkvt + (size_t)2*3*CC*CC;
    u16* w_1t   = w_pt   + (size_t)2*CC*CC;
    u16* w_2t   = w_1t   + (size_t)2*CC*FF;
    u16* w_ht   = w_2t   + (size_t)2*FF*CC;

    for (int l = 0; l < LL; l++) {
        const size_t wcc = (size_t)CC*CC, wcf = (size_t)CC*FF;
        cast_transpose_kernel<<<dim3(CC/64, CC/64), 256, 0, stream>>>(Wq + l*wcc, w_qkvt + l*3*wcc,           CC, CC);
        cast_transpose_kernel<<<dim3(CC/64, CC/64), 256, 0, stream>>>(Wk + l*wcc, w_qkvt + l*3*wcc + wcc,     CC, CC);
        cast_transpose_kernel<<<dim3(CC/64, CC/64), 256, 0, stream>>>(Wv + l*wcc, w_qkvt + l*3*wcc + 2*wcc,   CC, CC);
        cast_transpose_kernel<<<dim3(CC/64, CC/64), 256, 0, stream>>>(Wp + l*wcc, w_pt + l*wcc,               CC, CC);
        cast_transpose_kernel<<<dim3(FF/64, CC/64), 256, 0, stream>>>(W1 + l*wcf, w_1t + l*wcf,               CC, FF);
        cast_transpose_kernel<<<dim3(CC/64, FF/64), 256, 0, stream>>>(W2 + l*wcf, w_2t + l*wcf,               FF, CC);
    }
    cast_transpose_kernel<<<dim3(CC/64, CC/64), 256, 0, stream>>>(Whead, w_ht, CC, CC);

    embed_kernel<<<BT, 256, 0, stream>>>(idx, tok, pos, x);

    // grid sizes (1-D, swizzled): blocks = (N/BN) * (4096/BM)
    const int g_qkv  = (3*CC/128) * (BT/64);   // 12 * 64 = 768
    const int g_proj = (CC/64)    * (BT/64);   // 8 * 64 = 512
    const int g_fc1  = (FF/128)   * (BT/64);   // 16 * 64 = 1024
    const int g_fc2  = (CC/64)    * (BT/64);   // 512
    const int g_head = (VV/64)    * (BT/64);   // 512

    for (int s = 0; s < NSTEPS; s++) {
        for (int l = 0; l < LL; l++) {
            // attention
            ln_kernel<<<BT, 256, 0, stream>>>(x, ln1g + l*CC, ln1b + l*CC, xn);
            gemm_bt_kernel<64,128,0><<<g_qkv, 256, 0, stream>>>(
                xn, w_qkvt + (size_t)l*3*CC*CC, 3*CC, CC,
                bq + l*CC, bk + l*CC, bv + l*CC, nullptr, qb, kb, vtb);
            attn_mfma_kernel<<<dim3(TT/128, HH, BB), 256, 0, stream>>>(qb, kb, vtb, xn);
            gemm_bt_kernel<64,64,1><<<g_proj, 256, 0, stream>>>(
                xn, w_pt + (size_t)l*CC*CC, CC, CC,
                bp + l*CC, nullptr, nullptr, x, nullptr, nullptr, nullptr);
            // MLP
            ln_kernel<<<BT, 256, 0, stream>>>(x, ln2g + l*CC, ln2b + l*CC, xn);
            gemm_bt_kernel<64,128,2><<<g_fc1, 256, 0, stream>>>(
                xn, w_1t + (size_t)l*CC*FF, FF, CC,
                b1 + (size_t)l*FF, nullptr, nullptr, nullptr, hb, nullptr, nullptr);
            gemm_bt_kernel<64,64,1><<<g_fc2, 256, 0, stream>>>(
                hb, w_2t + (size_t)l*FF*CC, CC, FF,
                b2 + l*CC, nullptr, nullptr, x, nullptr, nullptr, nullptr);
        }
    }

    // final LN + head (fp32 logits)
    ln_kernel<<<BT, 256, 0, stream>>>(x, lnfg, lnfb, xn);
    gemm_bt_kernel<64,64,3><<<g_head, 256, 0, stream>>>(
        xn, w_ht, VV, CC, nullptr, nullptr, nullptr, (float*)d_out, nullptr, nullptr, nullptr);
}

// Round 6
// 1053.815 us; speedup vs baseline: 17.0484x; 1.1058x over previous
//
#include <hip/hip_runtime.h>
#include <hip/hip_bf16.h>
#include <math.h>

#define BB 8
#define TT 512
#define CC 512
#define HH 8
#define DH 64
#define LL 2
#define VV 512
#define NSTEPS 4
#define BT (BB*TT)
#define FF (4*CC)

typedef unsigned short u16;
typedef __bf16 bf16x8 __attribute__((ext_vector_type(8)));
typedef float f32x4 __attribute__((ext_vector_type(4)));

// fp32 -> bf16 bits, round-to-nearest-even
static __device__ __forceinline__ u16 f2bf(float f) {
    unsigned int u = __float_as_uint(f);
    unsigned int r = (u + 0x7fffu + ((u >> 16) & 1u)) >> 16;
    return (u16)r;
}

// async global->LDS, 16 bytes per lane (global_load_lds_dwordx4)
static __device__ __forceinline__ void async16(const void* g, void* l) {
    __builtin_amdgcn_global_load_lds((__attribute__((address_space(1))) void*)g,
                                     (__attribute__((address_space(3))) void*)l, 16, 0, 0);
}

// ---------------- embedding ----------------
__global__ void embed_kernel(const int* __restrict__ idx, const float* __restrict__ tok,
                             const float* __restrict__ pos, float* __restrict__ x) {
    int bt = blockIdx.x;
    int t  = threadIdx.x;
    int token = idx[bt];
    int posrow = bt % TT;
    x[(size_t)bt*CC + t]       = tok[token*CC + t]       + pos[posrow*CC + t];
    x[(size_t)bt*CC + t + 256] = tok[token*CC + t + 256] + pos[posrow*CC + t + 256];
}

// ---------------- layernorm fp32 in -> bf16 out ----------------
__global__ void ln_kernel(const float* __restrict__ x, const float* __restrict__ g,
                          const float* __restrict__ b, u16* __restrict__ out) {
    int row = blockIdx.x;
    int t = threadIdx.x;
    const float* xr = x + (size_t)row * CC;
    float v0 = xr[t], v1 = xr[t + 256];
    __shared__ float rs[256], rq[256];
    rs[t] = v0 + v1;
    rq[t] = v0 * v0 + v1 * v1;
    __syncthreads();
    for (int off = 128; off > 0; off >>= 1) {
        if (t < off) { rs[t] += rs[t + off]; rq[t] += rq[t + off]; }
        __syncthreads();
    }
    float mean = rs[0] * (1.0f / CC);
    float var  = rq[0] * (1.0f / CC) - mean * mean;
    float inv  = rsqrtf(var + 1e-5f);
    out[(size_t)row*CC + t]       = f2bf((v0 - mean) * inv * g[t]       + b[t]);
    out[(size_t)row*CC + t + 256] = f2bf((v1 - mean) * inv * g[t + 256] + b[t + 256]);
}

// ---------------- merged cast+transpose of ALL weights (one launch) ----------------
// Each block does one 64x64 tile: src fp32 [K][N] -> dst bf16 [N][K].
__global__ __launch_bounds__(256)
void cast_all_kernel(const float* __restrict__ Wq, const float* __restrict__ Wk,
                     const float* __restrict__ Wv, const float* __restrict__ Wp,
                     const float* __restrict__ W1, const float* __restrict__ W2,
                     const float* __restrict__ Wh,
                     u16* w_qkvt, u16* w_pt, u16* w_1t, u16* w_2t, u16* w_ht) {
    int bid = blockIdx.x;
    const float* src; u16* dst; int K, N, i0, j0;
    const size_t wcc = (size_t)CC*CC, wcf = (size_t)CC*FF;
    if (bid < 1536) {
        int l = bid / 768, r = bid % 768;
        if (r < 256) {
            int m = r / 64, t = r % 64;
            K = CC; N = CC;
            i0 = (t / 8) * 64; j0 = (t % 8) * 64;
            if      (m == 0) { src = Wq + l*wcc; dst = w_qkvt + (size_t)l*3*wcc; }
            else if (m == 1) { src = Wk + l*wcc; dst = w_qkvt + (size_t)l*3*wcc + wcc; }
            else if (m == 2) { src = Wv + l*wcc; dst = w_qkvt + (size_t)l*3*wcc + 2*wcc; }
            else             { src = Wp + l*wcc; dst = w_pt + (size_t)l*wcc; }
        } else if (r < 512) {
            int t = r - 256;               // W1: [CC][FF] -> [FF][CC]
            K = CC; N = FF;
            i0 = (t / 32) * 64; j0 = (t % 32) * 64;
            src = W1 + l*wcf; dst = w_1t + (size_t)l*wcf;
        } else {
            int t = r - 512;               // W2: [FF][CC] -> [CC][FF]
            K = FF; N = CC;
            i0 = (t / 8) * 64; j0 = (t % 8) * 64;
            src = W2 + l*wcf; dst = w_2t + (size_t)l*wcf;
        }
    } else {
        int t = bid - 1536;
        K = CC; N = CC;
        i0 = (t / 8) * 64; j0 = (t % 8) * 64;
        src = Wh; dst = w_ht;
    }
    __shared__ float tile[64][65];
    int tt = threadIdx.x;
    int rr = tt >> 2, cg = (tt & 3) * 16;
#pragma unroll
    for (int i = 0; i < 16; i++)
        tile[rr][cg + i] = src[(size_t)(i0 + rr) * N + j0 + cg + i];
    __syncthreads();
#pragma unroll
    for (int i = 0; i < 16; i++)
        dst[(size_t)(j0 + rr) * K + i0 + cg + i] = f2bf(tile[cg + i][rr]);
}

// ---------------- MFMA GEMM, double-buffered, BK=64 (2 x 32 sub-tiles) ----------------
// out = A[M,K](bf16) @ Bt[N,K]^T.  4 waves 2x2, per-wave (BM/2)x(BN/2).
// LDS sub-tile layout [ks][row][32] keeps 64 B row stride (all 32 banks used by ds_read_b128).
// Prefetch next K-tile via global_load_lds BEFORE computing current -> the barrier's
// vmcnt(0) drain is overlapped by a full tile of MFMA.
// EPI 0: fused QKV (q pre-scaled by 1/8; v transposed to [B][H][DH][T])
// EPI 1: bias + residual accumulate into fp32 outf
// EPI 2: bias + exact GELU -> bf16 outq
// EPI 3: plain fp32 out
template<int BM, int BN, int EPI>
__global__ __launch_bounds__(256)
void gemm_bt_kernel(const u16* __restrict__ A, const u16* __restrict__ Bt,
                    int N, int K,
                    const float* __restrict__ bias, const float* __restrict__ biask,
                    const float* __restrict__ biasv,
                    float* outf, u16* outq, u16* outk, u16* outvt) {
    constexpr int WM = BM / 2, WN = BN / 2;
    constexpr int TM = WM / 16, TN = WN / 16;
    __shared__ u16 lds_a[2][2][BM][32];
    __shared__ u16 lds_b[2][2][BN][32];
    int tid = threadIdx.x;
    int wid = tid >> 6, lane = tid & 63;
    int quad = lane >> 4, l15 = lane & 15;
    int wm = (wid & 1) * WM, wn = (wid >> 1) * WN;

    // XCD swizzle: lin&7 picks bm residue -> all bn-blocks of a bm on one XCD
    int NBN = N / BN;
    int lin = blockIdx.x;
    int x8 = lin & 7, slot = lin >> 3;
    int bn = slot % NBN;
    int bm = (slot / NBN) * 8 + x8;

    const int r2 = tid >> 2;          // 0..63
    const int c4 = (tid & 3) * 8;     // 0,8,16,24
    const size_t a0 = (size_t)bm * BM, b0 = (size_t)bn * BN;

    auto stage = [&](int buf, int kt) {
#pragma unroll
        for (int ks = 0; ks < 2; ks++) {
#pragma unroll
            for (int i = 0; i < BM/64; i++)
                async16(&A[(a0 + i*64 + r2) * K + kt + ks*32 + c4], &lds_a[buf][ks][i*64 + r2][c4]);
#pragma unroll
            for (int i = 0; i < BN/64; i++)
                async16(&Bt[(b0 + i*64 + r2) * K + kt + ks*32 + c4], &lds_b[buf][ks][i*64 + r2][c4]);
        }
    };

    f32x4 zero = {0.f, 0.f, 0.f, 0.f};
    f32x4 acc[TM][TN];
#pragma unroll
    for (int mi = 0; mi < TM; mi++)
#pragma unroll
        for (int ni = 0; ni < TN; ni++) acc[mi][ni] = zero;

    stage(0, 0);
    __syncthreads();
    const int NKT = K / 64;
    for (int kt = 0; kt < NKT; kt++) {
        int cur = kt & 1;
        if (kt + 1 < NKT) stage(cur ^ 1, (kt + 1) * 64);
#pragma unroll
        for (int ks = 0; ks < 2; ks++) {
            bf16x8 af[TM], bfr[TN];
#pragma unroll
            for (int mi = 0; mi < TM; mi++) af[mi]  = *(const bf16x8*)&lds_a[cur][ks][wm + mi*16 + l15][quad*8];
#pragma unroll
            for (int ni = 0; ni < TN; ni++) bfr[ni] = *(const bf16x8*)&lds_b[cur][ks][wn + ni*16 + l15][quad*8];
#pragma unroll
            for (int mi = 0; mi < TM; mi++)
#pragma unroll
                for (int ni = 0; ni < TN; ni++)
                    acc[mi][ni] = __builtin_amdgcn_mfma_f32_16x16x32_bf16(af[mi], bfr[ni], acc[mi][ni], 0, 0, 0);
        }
        __syncthreads();
    }

#pragma unroll
    for (int mi = 0; mi < TM; mi++)
#pragma unroll
        for (int ni = 0; ni < TN; ni++)
#pragma unroll
            for (int i = 0; i < 4; i++) {
                int row = bm*BM + wm + mi*16 + quad*4 + i;
                int col = bn*BN + wn + ni*16 + l15;
                float v = acc[mi][ni][i];
                if (EPI == 0) {
                    int region = col >> 9, cl = col & 511;
                    if (region == 0) {
                        v = (v + bias[cl]) * 0.125f;   // fold 1/sqrt(64) into q (exact pow2)
                        outq[(size_t)row*512 + cl] = f2bf(v);
                    } else if (region == 1) {
                        v += biask[cl];
                        outk[(size_t)row*512 + cl] = f2bf(v);
                    } else {
                        v += biasv[cl];
                        int bb = row >> 9, tpos = row & 511, hh = cl >> 6, dh = cl & 63;
                        outvt[(((size_t)(bb*8 + hh)*64 + dh) << 9) + tpos] = f2bf(v);
                    }
                } else if (EPI == 1) {
                    size_t idx2 = (size_t)row * N + col;
                    v += bias[col] + outf[idx2];
                    outf[idx2] = v;
                } else if (EPI == 2) {
                    v += bias[col];
                    v = 0.5f * v * (1.0f + erff(v * 0.70710678118654752f));
                    outq[(size_t)row * N + col] = f2bf(v);
                } else {
                    outf[(size_t)row * N + col] = v;
                }
            }
}

// ---------------- fused MFMA flash attention (64-q-row tiles, dbuf K/V) ----------------
// q (pre-scaled), k: bf16 [BT][C]; vt: bf16 [B][H][DH][T]; y: bf16 [BT][C]
// grid (T/64, H, B) = 512 blocks; 4 waves, wave w handles q-rows w*16..w*16+15.
__global__ __launch_bounds__(256)
void attn_mfma_kernel(const u16* __restrict__ q, const u16* __restrict__ k,
                      const u16* __restrict__ vt, u16* __restrict__ y) {
    __shared__ u16 lq[64][64];       // 8 KB
    __shared__ u16 lk[2][64][64];    // 16 KB
    __shared__ u16 lv[2][64][64];    // 16 KB (V^T: [dh][key])
    __shared__ u16 lp[4][16][64];    // 8 KB per-wave P round-trip
    int qt = blockIdx.x, h = blockIdx.y, b = blockIdx.z;
    int tid = threadIdx.x;
    int wid = tid >> 6, lane = tid & 63;
    int quad = lane >> 4, l15 = lane & 15;
    const int sr = tid >> 3;        // 0..31
    const int sc = (tid & 7) * 8;

    auto stageKV = [&](int buf, int kt) {
#pragma unroll
        for (int c = 0; c < 2; c++) {
            async16(&k[(size_t)(b*TT + kt*64 + c*32 + sr)*CC + h*DH + sc], &lk[buf][c*32 + sr][sc]);
            async16(&vt[((size_t)((b*HH + h)*DH + c*32 + sr))*TT + kt*64 + sc], &lv[buf][c*32 + sr][sc]);
        }
    };

#pragma unroll
    for (int c = 0; c < 2; c++)
        async16(&q[(size_t)(b*TT + qt*64 + c*32 + sr)*CC + h*DH + sc], &lq[c*32 + sr][sc]);
    stageKV(0, 0);
    __syncthreads();

    f32x4 zero = {0.f, 0.f, 0.f, 0.f};
    f32x4 acc_o[4];
    float m_st[4], l_st[4];
#pragma unroll
    for (int i = 0; i < 4; i++) { m_st[i] = -INFINITY; l_st[i] = 0.f; }
#pragma unroll
    for (int ni = 0; ni < 4; ni++) acc_o[ni] = zero;

    for (int kt = 0; kt < TT/64; kt++) {
        int cur = kt & 1;
        if (kt + 1 < TT/64) stageKV(cur ^ 1, kt + 1);

        // S = Q K^T  (16 q-rows x 64 keys per wave)
        f32x4 s[4];
#pragma unroll
        for (int ni = 0; ni < 4; ni++) s[ni] = zero;
#pragma unroll
        for (int ks = 0; ks < 2; ks++) {
            bf16x8 aq = *(const bf16x8*)&lq[wid*16 + l15][ks*32 + quad*8];
            bf16x8 bfr[4];
#pragma unroll
            for (int ni = 0; ni < 4; ni++) bfr[ni] = *(const bf16x8*)&lk[cur][ni*16 + l15][ks*32 + quad*8];
#pragma unroll
            for (int ni = 0; ni < 4; ni++)
                s[ni] = __builtin_amdgcn_mfma_f32_16x16x32_bf16(aq, bfr[ni], s[ni], 0, 0, 0);
        }

        // online softmax (q pre-scaled; rows quad*4+i)
#pragma unroll
        for (int i = 0; i < 4; i++) {
            float mx = -INFINITY;
#pragma unroll
            for (int ni = 0; ni < 4; ni++) mx = fmaxf(mx, s[ni][i]);
#pragma unroll
            for (int off = 1; off < 16; off <<= 1) mx = fmaxf(mx, __shfl_xor(mx, off));
            float mn = fmaxf(m_st[i], mx);
            float al = __expf(m_st[i] - mn);
            float rs = 0.f;
#pragma unroll
            for (int ni = 0; ni < 4; ni++) {
                float p = __expf(s[ni][i] - mn);
                s[ni][i] = p;
                rs += p;
            }
#pragma unroll
            for (int off = 1; off < 16; off <<= 1) rs += __shfl_xor(rs, off);
            l_st[i] = l_st[i] * al + rs;
            m_st[i] = mn;
#pragma unroll
            for (int ni = 0; ni < 4; ni++) acc_o[ni][i] *= al;
        }

        // P -> LDS (C-layout -> A-operand layout), per-wave region
#pragma unroll
        for (int ni = 0; ni < 4; ni++)
#pragma unroll
            for (int i = 0; i < 4; i++)
                lp[wid][quad*4 + i][ni*16 + l15] = f2bf(s[ni][i]);

        // O += P V
#pragma unroll
        for (int ks = 0; ks < 2; ks++) {
            bf16x8 pa = *(const bf16x8*)&lp[wid][l15][ks*32 + quad*8];
            bf16x8 vb[4];
#pragma unroll
            for (int ni = 0; ni < 4; ni++) vb[ni] = *(const bf16x8*)&lv[cur][ni*16 + l15][ks*32 + quad*8];
#pragma unroll
            for (int ni = 0; ni < 4; ni++)
                acc_o[ni] = __builtin_amdgcn_mfma_f32_16x16x32_bf16(pa, vb[ni], acc_o[ni], 0, 0, 0);
        }
        __syncthreads();
    }

#pragma unroll
    for (int i = 0; i < 4; i++) {
        float inv = 1.0f / l_st[i];
#pragma unroll
        for (int ni = 0; ni < 4; ni++) {
            int qrow = qt*64 + wid*16 + quad*4 + i;
            int col  = h*DH + ni*16 + l15;
            y[(size_t)(b*TT + qrow)*CC + col] = f2bf(acc_o[ni][i] * inv);
        }
    }
}

extern "C" void kernel_launch(void* const* d_in, const int* in_sizes, int n_in,
                              void* d_out, int out_size, void* d_ws, size_t ws_size,
                              hipStream_t stream) {
    const int*   idx   = (const int*)d_in[0];
    const float* tok   = (const float*)d_in[1];
    const float* pos   = (const float*)d_in[2];
    const float* ln1g  = (const float*)d_in[3];
    const float* ln1b  = (const float*)d_in[4];
    const float* Wq    = (const float*)d_in[5];
    const float* bq    = (const float*)d_in[6];
    const float* Wk    = (const float*)d_in[7];
    const float* bk    = (const float*)d_in[8];
    const float* Wv    = (const float*)d_in[9];
    const float* bv    = (const float*)d_in[10];
    const float* Wp    = (const float*)d_in[11];
    const float* bp    = (const float*)d_in[12];
    const float* ln2g  = (const float*)d_in[13];
    const float* ln2b  = (const float*)d_in[14];
    const float* W1    = (const float*)d_in[15];
    const float* b1    = (const float*)d_in[16];
    const float* W2    = (const float*)d_in[17];
    const float* b2    = (const float*)d_in[18];
    const float* lnfg  = (const float*)d_in[19];
    const float* lnfb  = (const float*)d_in[20];
    const float* Whead = (const float*)d_in[21];

    // ---- workspace layout (~40.5 MB) ----
    float* x  = (float*)d_ws;                       // BT*CC fp32
    u16* xn   = (u16*)(x + (size_t)BT*CC);          // BT*CC bf16
    u16* R    = xn + (size_t)BT*CC;
    u16* qb   = R;
    u16* kb   = R + (size_t)BT*CC;
    u16* vtb  = R + (size_t)2*BT*CC;
    u16* hb   = R;                                  // BT*FF spans region (q/k/vt dead in MLP)
    u16* w_qkvt = R + (size_t)4*BT*CC;
    u16* w_pt   = w_qkvt + (size_t)2*3*CC*CC;
    u16* w_1t   = w_pt   + (size_t)2*CC*CC;
    u16* w_2t   = w_1t   + (size_t)2*CC*FF;
    u16* w_ht   = w_2t   + (size_t)2*FF*CC;

    cast_all_kernel<<<1600, 256, 0, stream>>>(Wq, Wk, Wv, Wp, W1, W2, Whead,
                                              w_qkvt, w_pt, w_1t, w_2t, w_ht);
    embed_kernel<<<BT, 256, 0, stream>>>(idx, tok, pos, x);

    const int g_qkv  = (3*CC/128) * (BT/64);   // 768
    const int g_proj = (CC/64)    * (BT/64);   // 512
    const int g_fc1  = (FF/128)   * (BT/64);   // 1024
    const int g_fc2  = (CC/64)    * (BT/64);   // 512
    const int g_head = (VV/64)    * (BT/64);   // 512

    for (int s = 0; s < NSTEPS; s++) {
        for (int l = 0; l < LL; l++) {
            // attention
            ln_kernel<<<BT, 256, 0, stream>>>(x, ln1g + l*CC, ln1b + l*CC, xn);
            gemm_bt_kernel<64,128,0><<<g_qkv, 256, 0, stream>>>(
                xn, w_qkvt + (size_t)l*3*CC*CC, 3*CC, CC,
                bq + l*CC, bk + l*CC, bv + l*CC, nullptr, qb, kb, vtb);
            attn_mfma_kernel<<<dim3(TT/64, HH, BB), 256, 0, stream>>>(qb, kb, vtb, xn);
            gemm_bt_kernel<64,64,1><<<g_proj, 256, 0, stream>>>(
                xn, w_pt + (size_t)l*CC*CC, CC, CC,
                bp + l*CC, nullptr, nullptr, x, nullptr, nullptr, nullptr);
            // MLP
            ln_kernel<<<BT, 256, 0, stream>>>(x, ln2g + l*CC, ln2b + l*CC, xn);
            gemm_bt_kernel<64,128,2><<<g_fc1, 256, 0, stream>>>(
                xn, w_1t + (size_t)l*CC*FF, FF, CC,
                b1 + (size_t)l*FF, nullptr, nullptr, nullptr, hb, nullptr, nullptr);
            gemm_bt_kernel<64,64,1><<<g_fc2, 256, 0, stream>>>(
                hb, w_2t + (size_t)l*FF*CC, CC, FF,
                b2 + l*CC, nullptr, nullptr, x, nullptr, nullptr, nullptr);
        }
    }

    // final LN + head (fp32 logits)
    ln_kernel<<<BT, 256, 0, stream>>>(x, lnfg, lnfb, xn);
    gemm_bt_kernel<64,64,3><<<g_head, 256, 0, stream>>>(
        xn, w_ht, VV, CC, nullptr, nullptr, nullptr, (float*)d_out, nullptr, nullptr, nullptr);
}